// Round 1
// baseline (694.653 us; speedup 1.0000x reference)
//
#include <hip/hip_runtime.h>
#include <cstdint>
#include <cstddef>

// ---------------- constants ----------------
#define T_TOK 2048
#define HID   4096
#define NQH   32
#define NKVH  8
#define HD    128
#define QKV_N 6144   // 4096 q + 1024 k + 1024 v

typedef __bf16 bf16x8 __attribute__((ext_vector_type(8)));
typedef __bf16 bf16x4 __attribute__((ext_vector_type(4)));
typedef float  f32x4  __attribute__((ext_vector_type(4)));

#define AS1 __attribute__((address_space(1)))
#define AS3 __attribute__((address_space(3)))

__device__ __forceinline__ void gll16(const void* g, void* l) {
  __builtin_amdgcn_global_load_lds((const AS1 void*)g, (AS3 void*)l, 16, 0, 0);
}

// ---------------- fp32 -> bf16 convert (vec4) ----------------
__global__ __launch_bounds__(256) void k_convert(const float* __restrict__ in,
                                                 __bf16* __restrict__ out, int n4) {
  int i = blockIdx.x * 256 + threadIdx.x;
  if (i >= n4) return;
  float4 v = ((const float4*)in)[i];
  bf16x4 o;
  o[0] = (__bf16)v.x; o[1] = (__bf16)v.y; o[2] = (__bf16)v.z; o[3] = (__bf16)v.w;
  ((bf16x4*)out)[i] = o;
}

// ---------------- transpose fp32 [R][C] -> bf16 [C][R] ----------------
__global__ __launch_bounds__(256) void k_transpose(const float* __restrict__ in,
                                                   __bf16* __restrict__ out,
                                                   int R, int C) {
  __shared__ float tile[32][33];
  int c0 = blockIdx.x * 32, r0 = blockIdx.y * 32;
  int tx = threadIdx.x, ty = threadIdx.y;  // 32 x 8
#pragma unroll
  for (int k = 0; k < 4; ++k)
    tile[ty + k*8][tx] = in[(size_t)(r0 + ty + k*8) * C + c0 + tx];
  __syncthreads();
#pragma unroll
  for (int k = 0; k < 4; ++k)
    out[(size_t)(c0 + ty + k*8) * R + r0 + tx] = (__bf16)tile[tx][ty + k*8];
}

// ---------------- bf16 GEMM: C[M][N] = A[M][K] @ Bt[N][K]^T, fp32 out ----------
// 128x128 tile, BK=64, 4 waves (2x2), 16x16x32 MFMA, global_load_lds staging
// with XOR-swizzled global source (LDS stays linear), swizzled ds_read_b128.
__global__ __launch_bounds__(256) void k_gemm_bt(const __bf16* __restrict__ A,
                                                 const __bf16* __restrict__ Bt,
                                                 float* __restrict__ C,
                                                 int M, int N, int K) {
  __shared__ alignas(16) __bf16 As[128 * 64];
  __shared__ alignas(16) __bf16 Bs[128 * 64];
  const int tid  = threadIdx.x;
  const int lane = tid & 63;
  const int w    = tid >> 6;        // wave 0..3
  const int wr   = w >> 1, wc = w & 1;
  const int l16  = lane & 15, lg = lane >> 4;
  const int bm = blockIdx.y, bn = blockIdx.x;

  f32x4 acc[4][4] = {};
  char* Asb = (char*)As;
  char* Bsb = (char*)Bs;

  const int nkt = K >> 6;
  for (int kt = 0; kt < nkt; ++kt) {
    const int k0 = kt << 6;
    // -------- stage A,B tiles: 1024 chunks of 16B each, 8 gll per thread ----
#pragma unroll
    for (int j = 0; j < 4; ++j) {
      int c = (w * 4 + j) * 64 + lane;   // flat 16B-chunk id 0..1023
      int r = c >> 3, p = c & 7;         // row 0..127, phys chunk 0..7
      int sc = p ^ (r & 7);              // swizzled source chunk
      gll16(A  + (size_t)(bm * 128 + r) * K + k0 + sc * 8, Asb + (w * 4 + j) * 1024);
      gll16(Bt + (size_t)(bn * 128 + r) * K + k0 + sc * 8, Bsb + (w * 4 + j) * 1024);
    }
    __syncthreads();
    // -------- compute: 2 k-chunks of 32, 4x4 fragment grid -----------------
#pragma unroll
    for (int mk = 0; mk < 2; ++mk) {
      bf16x8 af[4], bfr[4];
#pragma unroll
      for (int mi = 0; mi < 4; ++mi) {
        int row = wr * 64 + mi * 16 + l16;
        int g = mk * 4 + lg;
        af[mi] = *(const bf16x8*)(Asb + row * 128 + ((g ^ (row & 7)) * 16));
      }
#pragma unroll
      for (int ni = 0; ni < 4; ++ni) {
        int row = wc * 64 + ni * 16 + l16;
        int g = mk * 4 + lg;
        bfr[ni] = *(const bf16x8*)(Bsb + row * 128 + ((g ^ (row & 7)) * 16));
      }
#pragma unroll
      for (int mi = 0; mi < 4; ++mi)
#pragma unroll
        for (int ni = 0; ni < 4; ++ni)
          acc[mi][ni] = __builtin_amdgcn_mfma_f32_16x16x32_bf16(af[mi], bfr[ni], acc[mi][ni], 0, 0, 0);
    }
    __syncthreads();
  }
  // -------- epilogue: C/D layout col=lane&15, row=(lane>>4)*4+reg -----------
#pragma unroll
  for (int mi = 0; mi < 4; ++mi)
#pragma unroll
    for (int ni = 0; ni < 4; ++ni) {
      int row = bm * 128 + wr * 64 + mi * 16 + lg * 4;
      int col = bn * 128 + wc * 64 + ni * 16 + l16;
#pragma unroll
      for (int r = 0; r < 4; ++r)
        C[(size_t)(row + r) * N + col] = acc[mi][ni][r];
    }
}

// ---------------- per-(token, head-slot) RMSNorm + RoPE -> bf16 ------------
// slot 0..31: q heads (norm+rope), 32..39: k heads (norm+rope), 40..47: v (convert)
__global__ __launch_bounds__(64) void k_norm_rope(const float* __restrict__ qkv,
                                                  const int* __restrict__ pos,
                                                  const float* __restrict__ qw,
                                                  const float* __restrict__ kw,
                                                  __bf16* __restrict__ qo,
                                                  __bf16* __restrict__ ko,
                                                  __bf16* __restrict__ vo) {
  const int slot = blockIdx.x;   // 0..47
  const int t    = blockIdx.y;   // token
  const int i    = threadIdx.x;  // 0..63
  const int off  = (slot < 32) ? slot * 128
                 : (slot < 40) ? 4096 + (slot - 32) * 128
                                : 5120 + (slot - 40) * 128;
  const float* base = qkv + (size_t)t * QKV_N + off;
  float x1 = base[i], x2 = base[i + 64];
  if (slot >= 40) {
    __bf16* o = vo + ((size_t)t * NKVH + (slot - 40)) * HD;
    o[i] = (__bf16)x1; o[i + 64] = (__bf16)x2;
    return;
  }
  float ss = x1 * x1 + x2 * x2;
#pragma unroll
  for (int m = 32; m >= 1; m >>= 1) ss += __shfl_xor(ss, m);
  float rinv = rsqrtf(ss * (1.0f / 128.0f) + 1e-6f);
  const float* wn = (slot < 32) ? qw : kw;
  float n1 = x1 * rinv * wn[i];
  float n2 = x2 * rinv * wn[i + 64];
  // inv_freq_i = 1e6^(-i/64) = exp(-i * ln(1e6)/64)
  float fr = (float)pos[t] * expf((float)i * -0.21586735246819178f);
  float cs = cosf(fr), sn = sinf(fr);
  float o1 = n1 * cs - n2 * sn;
  float o2 = n2 * cs + n1 * sn;
  __bf16* o = (slot < 32) ? (qo + ((size_t)t * NQH + slot) * HD)
                          : (ko + ((size_t)t * NKVH + (slot - 32)) * HD);
  o[i] = (__bf16)o1;
  o[i + 64] = (__bf16)o2;
}

// ---------------- causal GQA flash attention --------------------------------
// block = 4 waves; wave w owns 16 q-rows. KVBLK=32. Swapped QK^T: mfma(K, Q)
// puts kv lane-local. K staged via global_load_lds w/ swizzled src; V staged
// transposed (Vt[128][32]) by registers; P bounced through per-wave LDS.
__global__ __launch_bounds__(256) void k_attn(const __bf16* __restrict__ Q,
                                              const __bf16* __restrict__ K,
                                              const __bf16* __restrict__ V,
                                              __bf16* __restrict__ O) {
  __shared__ alignas(16) __bf16 Ks[32 * 128];   // [kv][hd], chunk-XOR swizzle
  __shared__ alignas(16) __bf16 Vs[128 * 32];   // Vt[hd][kv], bits4-5 swizzle
  __shared__ alignas(16) __bf16 Ps[4 * 512];    // per-wave P[16 q][32 kv]
  const int h   = blockIdx.y;
  const int kvh = h >> 2;
  const int q0  = blockIdx.x * 64;
  const int tid = threadIdx.x, lane = tid & 63, w = tid >> 6;
  const int l16 = lane & 15, lg = lane >> 4;
  const int qw_ = q0 + w * 16;
  const int qrow = qw_ + l16;
  char* Ksb = (char*)Ks;
  char* Vsb = (char*)Vs;
  char* Pw  = (char*)Ps + w * 1024;

  // Q fragments (held whole kernel): lane = Q[qrow][kc*32 + lg*8 .. +7]
  bf16x8 qf[4];
#pragma unroll
  for (int kc = 0; kc < 4; ++kc)
    qf[kc] = *(const bf16x8*)&Q[((size_t)qrow * NQH + h) * HD + kc * 32 + lg * 8];

  float m_run = -1e30f, l_run = 0.f;
  f32x4 o[8] = {};

  const int ntiles = q0 / 32 + 2;
  for (int tt = 0; tt < ntiles; ++tt) {
    const int s0 = tt * 32;
    // ---- stage K [32][128]: 512 chunks, global_load_lds w/ swizzled source
#pragma unroll
    for (int j = 0; j < 2; ++j) {
      int c = (w * 2 + j) * 64 + lane;
      int r = c >> 4, p = c & 15;
      int sc = p ^ (r & 7);
      gll16(&K[(((size_t)(s0 + r)) * NKVH + kvh) * HD + sc * 8], Ksb + (w * 2 + j) * 1024);
    }
    // ---- stage Vt[128][32] via regs (transpose), swizzle byte^=((d&3)<<4)
#pragma unroll
    for (int j = 0; j < 2; ++j) {
      int c = tid + 256 * j;
      int s = c >> 4, dc = c & 15;
      bf16x8 v = *(const bf16x8*)&V[(((size_t)(s0 + s)) * NKVH + kvh) * HD + dc * 8];
#pragma unroll
      for (int e = 0; e < 8; ++e) {
        int d = dc * 8 + e;
        *((__bf16*)(Vsb + d * 64 + ((s * 2) ^ ((d & 3) << 4)))) = v[e];
      }
    }
    __syncthreads();

    // ---- S^T = K @ Q^T : lane holds S[q=l16][kv = sub*16 + lg*4 + r]
    f32x4 sac[2] = {};
#pragma unroll
    for (int sub = 0; sub < 2; ++sub)
#pragma unroll
      for (int kc = 0; kc < 4; ++kc) {
        int row = sub * 16 + l16;
        int g = kc * 4 + lg;
        bf16x8 kf = *(const bf16x8*)(Ksb + row * 256 + ((g ^ (row & 7)) * 16));
        sac[sub] = __builtin_amdgcn_mfma_f32_16x16x32_bf16(kf, qf[kc], sac[sub], 0, 0, 0);
      }

    // ---- scale + causal mask + online softmax (q row = l16)
    float p[8];
    float mt = -1e30f;
#pragma unroll
    for (int sub = 0; sub < 2; ++sub)
#pragma unroll
      for (int r = 0; r < 4; ++r) {
        int kvg = s0 + sub * 16 + lg * 4 + r;
        float sv = sac[sub][r] * 0.08838834764831845f;
        sv = (kvg > qrow) ? -1e30f : sv;
        p[sub * 4 + r] = sv;
        mt = fmaxf(mt, sv);
      }
    mt = fmaxf(mt, __shfl_xor(mt, 16));
    mt = fmaxf(mt, __shfl_xor(mt, 32));
    float m_new = fmaxf(m_run, mt);
    float corr = expf(m_run - m_new);
    float rs = 0.f;
#pragma unroll
    for (int u = 0; u < 8; ++u) { p[u] = expf(p[u] - m_new); rs += p[u]; }
    rs += __shfl_xor(rs, 16);
    rs += __shfl_xor(rs, 32);
    l_run = l_run * corr + rs;
    m_run = m_new;

    // ---- rescale O (O rows are q = lg*4 + r -> fetch corr via shfl)
#pragma unroll
    for (int r = 0; r < 4; ++r) {
      float c4 = __shfl(corr, lg * 4 + r);
#pragma unroll
      for (int d8 = 0; d8 < 8; ++d8) o[d8][r] *= c4;
    }

    // ---- P -> LDS (bf16), swizzle byte-in-row ^= ((q&3)<<4)
#pragma unroll
    for (int sub = 0; sub < 2; ++sub) {
      bf16x4 pb;
#pragma unroll
      for (int r = 0; r < 4; ++r) pb[r] = (__bf16)p[sub * 4 + r];
      *(bf16x4*)(Pw + l16 * 64 + ((sub * 32 + lg * 8) ^ ((l16 & 3) << 4))) = pb;
    }

    // ---- PV: A = P[16][32] (row q = l16), B = V via Vt rows
    bf16x8 pa = *(const bf16x8*)(Pw + l16 * 64 + ((lg * 16) ^ ((l16 & 3) << 4)));
#pragma unroll
    for (int d8 = 0; d8 < 8; ++d8) {
      int d = d8 * 16 + l16;
      bf16x8 vf = *(const bf16x8*)(Vsb + d * 64 + ((lg * 16) ^ ((d & 3) << 4)));
      o[d8] = __builtin_amdgcn_mfma_f32_16x16x32_bf16(pa, vf, o[d8], 0, 0, 0);
    }
    __syncthreads();
  }

  // ---- epilogue: O rows q = lg*4+r, cols d = d8*16 + l16
#pragma unroll
  for (int r = 0; r < 4; ++r) {
    float li = 1.0f / __shfl(l_run, lg * 4 + r);
    int qg = qw_ + lg * 4 + r;
#pragma unroll
    for (int d8 = 0; d8 < 8; ++d8)
      O[((size_t)qg * NQH + h) * HD + d8 * 16 + l16] = (__bf16)(o[d8][r] * li);
  }
}

// ---------------- launch ----------------------------------------------------
extern "C" void kernel_launch(void* const* d_in, const int* in_sizes, int n_in,
                              void* d_out, int out_size, void* d_ws, size_t ws_size,
                              hipStream_t stream) {
  const int*   positions = (const int*)d_in[0];
  const float* hidden    = (const float*)d_in[1];
  const float* w_qkv     = (const float*)d_in[2];
  const float* w_o       = (const float*)d_in[3];
  const float* q_norm    = (const float*)d_in[4];
  const float* k_norm    = (const float*)d_in[5];
  float* out = (float*)d_out;

  char* ws = (char*)d_ws;
  // layout (aliased; stream order makes reuse safe):
  //   [0,  50.3MB)  wqkv_t bf16 [6144][4096]   -- dead after gemm1; then q/k/v
  //   [50.3, 83.9)  wo_t   bf16 [4096][4096]
  //   [83.9,100.7)  hidden bf16 [2048][4096]   -- dead after gemm1; then attn_out
  //   [100.7,151.0) qkv    f32  [2048][6144]
  __bf16* wqkv_t   = (__bf16*)ws;
  __bf16* wo_t     = (__bf16*)(ws + 50331648);
  __bf16* hidden_b = (__bf16*)(ws + 83886080);
  float*  qkv      = (float*)(ws + 100663296);
  __bf16* qb = (__bf16*)ws;                   // 16.8MB (over dead wqkv_t)
  __bf16* kb = (__bf16*)(ws + 16777216);      // 4.2MB
  __bf16* vb = (__bf16*)(ws + 20971520);      // 4.2MB
  __bf16* attn_o = hidden_b;                  // over dead hidden_b

  k_convert<<<dim3((T_TOK * HID / 4 + 255) / 256), 256, 0, stream>>>(hidden, hidden_b, T_TOK * HID / 4);
  k_transpose<<<dim3(QKV_N / 32, HID / 32), dim3(32, 8), 0, stream>>>(w_qkv, wqkv_t, HID, QKV_N);
  k_transpose<<<dim3(HID / 32, HID / 32), dim3(32, 8), 0, stream>>>(w_o, wo_t, HID, HID);
  k_gemm_bt<<<dim3(QKV_N / 128, T_TOK / 128), 256, 0, stream>>>(hidden_b, wqkv_t, qkv, T_TOK, QKV_N, HID);
  k_norm_rope<<<dim3(48, T_TOK), 64, 0, stream>>>(qkv, positions, q_norm, k_norm, qb, kb, vb);
  k_attn<<<dim3(T_TOK / 64, NQH), 256, 0, stream>>>(qb, kb, vb, attn_o);
  k_gemm_bt<<<dim3(HID / 128, T_TOK / 128), 256, 0, stream>>>(attn_o, wo_t, out, T_TOK, HID, HID);
}

// Round 2
// 382.380 us; speedup vs baseline: 1.8167x; 1.8167x over previous
//
#include <hip/hip_runtime.h>
#include <cstdint>
#include <cstddef>

// ---------------- constants ----------------
#define T_TOK 2048
#define HID   4096
#define NQH   32
#define NKVH  8
#define HD    128
#define QKV_N 6144   // 4096 q + 1024 k + 1024 v

typedef __bf16 bf16x8 __attribute__((ext_vector_type(8)));
typedef __bf16 bf16x4 __attribute__((ext_vector_type(4)));
typedef float  f32x4  __attribute__((ext_vector_type(4)));
typedef float  f32x16 __attribute__((ext_vector_type(16)));

#define AS1 __attribute__((address_space(1)))
#define AS3 __attribute__((address_space(3)))

__device__ __forceinline__ void gll16(const void* g, void* l) {
  __builtin_amdgcn_global_load_lds((const AS1 void*)g, (AS3 void*)l, 16, 0, 0);
}

// ---------------- fp32 -> bf16 convert (vec4) ----------------
__global__ __launch_bounds__(256) void k_convert(const float* __restrict__ in,
                                                 __bf16* __restrict__ out, int n4) {
  int i = blockIdx.x * 256 + threadIdx.x;
  if (i >= n4) return;
  float4 v = ((const float4*)in)[i];
  bf16x4 o;
  o[0] = (__bf16)v.x; o[1] = (__bf16)v.y; o[2] = (__bf16)v.z; o[3] = (__bf16)v.w;
  ((bf16x4*)out)[i] = o;
}

// ---------------- transpose fp32 [R][C] -> bf16 [C][R] ----------------
__global__ __launch_bounds__(256) void k_transpose(const float* __restrict__ in,
                                                   __bf16* __restrict__ out,
                                                   int R, int C) {
  __shared__ float tile[32][33];
  int c0 = blockIdx.x * 32, r0 = blockIdx.y * 32;
  int tx = threadIdx.x, ty = threadIdx.y;  // 32 x 8
#pragma unroll
  for (int k = 0; k < 4; ++k)
    tile[ty + k*8][tx] = in[(size_t)(r0 + ty + k*8) * C + c0 + tx];
  __syncthreads();
#pragma unroll
  for (int k = 0; k < 4; ++k)
    out[(size_t)(c0 + ty + k*8) * R + r0 + tx] = (__bf16)tile[tx][ty + k*8];
}

// ---------------- bf16 GEMM: C[M][N] = A[M][K] @ Bt[N][K]^T, fp32 out ----------
__global__ __launch_bounds__(256) void k_gemm_bt(const __bf16* __restrict__ A,
                                                 const __bf16* __restrict__ Bt,
                                                 float* __restrict__ C,
                                                 int M, int N, int K) {
  __shared__ alignas(16) __bf16 As[128 * 64];
  __shared__ alignas(16) __bf16 Bs[128 * 64];
  const int tid  = threadIdx.x;
  const int lane = tid & 63;
  const int w    = tid >> 6;        // wave 0..3
  const int wr   = w >> 1, wc = w & 1;
  const int l16  = lane & 15, lg = lane >> 4;
  const int bm = blockIdx.y, bn = blockIdx.x;

  f32x4 acc[4][4] = {};
  char* Asb = (char*)As;
  char* Bsb = (char*)Bs;

  const int nkt = K >> 6;
  for (int kt = 0; kt < nkt; ++kt) {
    const int k0 = kt << 6;
#pragma unroll
    for (int j = 0; j < 4; ++j) {
      int c = (w * 4 + j) * 64 + lane;   // flat 16B-chunk id 0..1023
      int r = c >> 3, p = c & 7;         // row 0..127, phys chunk 0..7
      int sc = p ^ (r & 7);              // swizzled source chunk
      gll16(A  + (size_t)(bm * 128 + r) * K + k0 + sc * 8, Asb + (w * 4 + j) * 1024);
      gll16(Bt + (size_t)(bn * 128 + r) * K + k0 + sc * 8, Bsb + (w * 4 + j) * 1024);
    }
    __syncthreads();
#pragma unroll
    for (int mk = 0; mk < 2; ++mk) {
      bf16x8 af[4], bfr[4];
#pragma unroll
      for (int mi = 0; mi < 4; ++mi) {
        int row = wr * 64 + mi * 16 + l16;
        int g = mk * 4 + lg;
        af[mi] = *(const bf16x8*)(Asb + row * 128 + ((g ^ (row & 7)) * 16));
      }
#pragma unroll
      for (int ni = 0; ni < 4; ++ni) {
        int row = wc * 64 + ni * 16 + l16;
        int g = mk * 4 + lg;
        bfr[ni] = *(const bf16x8*)(Bsb + row * 128 + ((g ^ (row & 7)) * 16));
      }
#pragma unroll
      for (int mi = 0; mi < 4; ++mi)
#pragma unroll
        for (int ni = 0; ni < 4; ++ni)
          acc[mi][ni] = __builtin_amdgcn_mfma_f32_16x16x32_bf16(af[mi], bfr[ni], acc[mi][ni], 0, 0, 0);
    }
    __syncthreads();
  }
#pragma unroll
  for (int mi = 0; mi < 4; ++mi)
#pragma unroll
    for (int ni = 0; ni < 4; ++ni) {
      int row = bm * 128 + wr * 64 + mi * 16 + lg * 4;
      int col = bn * 128 + wc * 64 + ni * 16 + l16;
#pragma unroll
      for (int r = 0; r < 4; ++r)
        C[(size_t)(row + r) * N + col] = acc[mi][ni][r];
    }
}

// ---------------- per-(token, head-slot) RMSNorm + RoPE -> bf16 ------------
// slot 0..31: q heads (norm+rope+log2-scale), 32..39: k heads (norm+rope),
// 40..47: v heads (convert + transpose to Vt[kvh][d][T])
__global__ __launch_bounds__(64) void k_norm_rope(const float* __restrict__ qkv,
                                                  const int* __restrict__ pos,
                                                  const float* __restrict__ qw,
                                                  const float* __restrict__ kw,
                                                  __bf16* __restrict__ qo,
                                                  __bf16* __restrict__ ko,
                                                  __bf16* __restrict__ vto) {
  const int slot = blockIdx.x;   // 0..47
  const int t    = blockIdx.y;   // token
  const int i    = threadIdx.x;  // 0..63
  const int off  = (slot < 32) ? slot * 128
                 : (slot < 40) ? 4096 + (slot - 32) * 128
                                : 5120 + (slot - 40) * 128;
  const float* base = qkv + (size_t)t * QKV_N + off;
  float x1 = base[i], x2 = base[i + 64];
  if (slot >= 40) {
    // Vt[kvh][d][T]
    __bf16* o = vto + ((size_t)(slot - 40) * HD) * T_TOK + t;
    o[(size_t)i * T_TOK] = (__bf16)x1;
    o[(size_t)(i + 64) * T_TOK] = (__bf16)x2;
    return;
  }
  float ss = x1 * x1 + x2 * x2;
#pragma unroll
  for (int m = 32; m >= 1; m >>= 1) ss += __shfl_xor(ss, m);
  float rinv = rsqrtf(ss * (1.0f / 128.0f) + 1e-6f);
  const float* wn = (slot < 32) ? qw : kw;
  float n1 = x1 * rinv * wn[i];
  float n2 = x2 * rinv * wn[i + 64];
  float fr = (float)pos[t] * expf((float)i * -0.21586735246819178f);
  float cs = cosf(fr), sn = sinf(fr);
  float o1 = n1 * cs - n2 * sn;
  float o2 = n2 * cs + n1 * sn;
  if (slot < 32) {
    // fold softmax scale (1/sqrt(128)) and log2(e) into Q
    const float QSC = 0.08838834764831845f * 1.4426950408889634f;
    __bf16* o = qo + ((size_t)t * NQH + slot) * HD;
    o[i] = (__bf16)(o1 * QSC);
    o[i + 64] = (__bf16)(o2 * QSC);
  } else {
    __bf16* o = ko + ((size_t)t * NKVH + (slot - 32)) * HD;
    o[i] = (__bf16)o1;
    o[i + 64] = (__bf16)o2;
  }
}

// ---------------- causal GQA flash attention (32x32 swapped-operand) ---------
// block = (kvh, 32 q-rows); 4 waves = 4 q-heads of the GQA group sharing K/V.
// KVBLK=64. Swapped QK^T: mfma(K,Q) -> lane owns one q-row's scores (in-reg
// softmax). Swapped PV: mfma(Vt,P^T) -> O^T stays q-lane-local.
__global__ __launch_bounds__(256, 2) void k_attn(const __bf16* __restrict__ Q,
                                                 const __bf16* __restrict__ K,
                                                 const __bf16* __restrict__ Vt,
                                                 __bf16* __restrict__ O) {
  __shared__ alignas(16) __bf16 Ks[64 * 128];    // [kv][d], chunk swz c^(r&15)
  __shared__ alignas(16) __bf16 Vts[128 * 64];   // [d][kv], chunk swz c^(r&7)
  const int bid = blockIdx.x;
  const int kvh = bid & 7;           // kvh == XCD -> K/V L2-local
  const int qc  = bid >> 3;          // 0..63
  const int tid = threadIdx.x, lane = tid & 63, w = tid >> 6;
  const int l31 = lane & 31, hi = lane >> 5;
  const int h  = kvh * 4 + w;        // global q-head
  const int q0 = qc * 32;
  const int qrow = q0 + l31;
  char* Ksb = (char*)Ks;
  char* Vtb = (char*)Vts;

  // Q fragments: qf[dc] = Q[qrow][dc*16 + hi*8 .. +7]
  bf16x8 qf[8];
  {
    const __bf16* qp = Q + ((size_t)qrow * NQH + h) * HD + hi * 8;
#pragma unroll
    for (int dc = 0; dc < 8; ++dc)
      qf[dc] = *(const bf16x8*)(qp + dc * 16);
  }

  // per-thread staging source offsets (elements), swizzled
  size_t ksrc[4], vsrc[4];
#pragma unroll
  for (int j = 0; j < 4; ++j) {
    int kr = w * 16 + j * 4 + (lane >> 4);             // K tile row 0..63
    ksrc[j] = ((size_t)kr * NKVH + kvh) * HD + (size_t)(((lane & 15) ^ (kr & 15)) * 8);
    int vr = w * 32 + j * 8 + (lane >> 3);             // Vt tile row 0..127
    vsrc[j] = ((size_t)(kvh * HD + vr)) * T_TOK + (size_t)(((lane & 7) ^ (vr & 7)) * 8);
  }

  float m_run = -3.0e38f, l_run = 0.f;
  f32x16 ot[4] = {};   // O^T[d=dt*32+pat][q=l31]

  const int ntiles = (qc >> 1) + 1;
  for (int tt = 0; tt < ntiles; ++tt) {
    const int s0 = tt * 64;
    // ---- stage K[64][128] and Vt[128][64] (16KB each) ----
#pragma unroll
    for (int j = 0; j < 4; ++j) {
      gll16(K + (size_t)s0 * (NKVH * HD) + ksrc[j], Ksb + (w * 4 + j) * 1024);
      gll16(Vt + (size_t)s0 + vsrc[j], Vtb + (w * 4 + j) * 1024);
    }
    __syncthreads();

    // ---- QK^T: S^T[kv][q], lane: q=l31, kv = 32hf + (r&3)+8(r>>2)+4hi ----
    f32x16 sac[2] = {};
#pragma unroll
    for (int hf = 0; hf < 2; ++hf) {
      int krow = hf * 32 + l31;
#pragma unroll
      for (int dc = 0; dc < 8; ++dc) {
        bf16x8 kf = *(const bf16x8*)(Ksb + krow * 256 + (((dc * 2 + hi) ^ (krow & 15)) * 16));
        sac[hf] = __builtin_amdgcn_mfma_f32_32x32x16_bf16(kf, qf[dc], sac[hf], 0, 0, 0);
      }
    }

    // ---- mask + online softmax (log2 domain; scale folded into Q) ----
    float pv[32];
    if (s0 + 64 > q0) {
#pragma unroll
      for (int hf = 0; hf < 2; ++hf)
#pragma unroll
        for (int r = 0; r < 16; ++r) {
          int kvg = s0 + hf * 32 + (r & 3) + ((r >> 2) * 8) + hi * 4;
          pv[hf * 16 + r] = (kvg > qrow) ? -3.0e38f : sac[hf][r];
        }
    } else {
#pragma unroll
      for (int hf = 0; hf < 2; ++hf)
#pragma unroll
        for (int r = 0; r < 16; ++r) pv[hf * 16 + r] = sac[hf][r];
    }
    float t16[16];
#pragma unroll
    for (int i = 0; i < 16; ++i) t16[i] = fmaxf(pv[i], pv[i + 16]);
#pragma unroll
    for (int i = 0; i < 8; ++i) t16[i] = fmaxf(t16[i], t16[i + 8]);
#pragma unroll
    for (int i = 0; i < 4; ++i) t16[i] = fmaxf(t16[i], t16[i + 4]);
    float mt = fmaxf(fmaxf(t16[0], t16[1]), fmaxf(t16[2], t16[3]));
    mt = fmaxf(mt, __shfl_xor(mt, 32));
    // defer-max (T13): only rescale when max grew by > 10 (log2 domain)
    if (!__all(mt - m_run <= 10.0f)) {
      float m_new = fmaxf(m_run, mt);
      float corr = exp2f(m_run - m_new);
      l_run *= corr;
#pragma unroll
      for (int dt = 0; dt < 4; ++dt)
#pragma unroll
        for (int r = 0; r < 16; ++r) ot[dt][r] *= corr;
      m_run = m_new;
    }
#pragma unroll
    for (int i = 0; i < 32; ++i) pv[i] = exp2f(pv[i] - m_run);
#pragma unroll
    for (int i = 0; i < 16; ++i) t16[i] = pv[i] + pv[i + 16];
#pragma unroll
    for (int i = 0; i < 8; ++i) t16[i] += t16[i + 8];
#pragma unroll
    for (int i = 0; i < 4; ++i) t16[i] += t16[i + 4];
    float rs = (t16[0] + t16[1]) + (t16[2] + t16[3]);
    rs += __shfl_xor(rs, 32);
    l_run += rs;

    // ---- P -> bf16 words (cvt_pk), per-kv-chunk cross-half exchange, PV ----
    uint32_t wds[16];
#pragma unroll
    for (int i = 0; i < 16; ++i) {
      uint32_t r;
      asm("v_cvt_pk_bf16_f32 %0, %1, %2" : "=v"(r) : "v"(pv[2 * i]), "v"(pv[2 * i + 1]));
      wds[i] = r;
    }
#pragma unroll
    for (int c = 0; c < 4; ++c) {
      const int base = (c >> 1) * 8 + (c & 1) * 4;
      uint32_t sa = hi ? wds[base + 0] : wds[base + 2];
      uint32_t sb = hi ? wds[base + 1] : wds[base + 3];
      uint32_t ra = __shfl_xor(sa, 32);
      uint32_t rb = __shfl_xor(sb, 32);
      union { uint32_t u[4]; bf16x8 v; } pf;
      pf.u[0] = hi ? ra : wds[base + 0];
      pf.u[1] = hi ? rb : wds[base + 1];
      pf.u[2] = hi ? wds[base + 2] : ra;
      pf.u[3] = hi ? wds[base + 3] : rb;
#pragma unroll
      for (int dt = 0; dt < 4; ++dt) {
        int vrow = dt * 32 + l31;
        bf16x8 vf = *(const bf16x8*)(Vtb + vrow * 128 + (((c * 2 + hi) ^ (vrow & 7)) * 16));
        ot[dt] = __builtin_amdgcn_mfma_f32_32x32x16_bf16(vf, pf.v, ot[dt], 0, 0, 0);
      }
    }
    __syncthreads();
  }

  // ---- epilogue: per-wave LDS bounce for coalesced O store ----
  float inv = 1.0f / l_run;
  char* Ob = Ksb + w * 8192;   // 4 waves x 8KB over Ks+Vts (loop barrier passed)
#pragma unroll
  for (int dt = 0; dt < 4; ++dt)
#pragma unroll
    for (int r = 0; r < 16; ++r) {
      int d = dt * 32 + (r & 3) + ((r >> 2) * 8) + hi * 4;
      *(__bf16*)(Ob + l31 * 256 + ((d * 2) ^ ((l31 & 7) << 4))) = (__bf16)(ot[dt][r] * inv);
    }
#pragma unroll
  for (int pass = 0; pass < 8; ++pass) {
    int q = pass * 4 + (lane >> 4);
    int ch = lane & 15;
    bf16x8 vvv = *(const bf16x8*)(Ob + q * 256 + ((ch ^ (q & 7)) * 16));
    *(bf16x8*)(O + ((size_t)(q0 + q) * NQH + h) * HD + ch * 8) = vvv;
  }
}

// ---------------- launch ----------------------------------------------------
extern "C" void kernel_launch(void* const* d_in, const int* in_sizes, int n_in,
                              void* d_out, int out_size, void* d_ws, size_t ws_size,
                              hipStream_t stream) {
  const int*   positions = (const int*)d_in[0];
  const float* hidden    = (const float*)d_in[1];
  const float* w_qkv     = (const float*)d_in[2];
  const float* w_o       = (const float*)d_in[3];
  const float* q_norm    = (const float*)d_in[4];
  const float* k_norm    = (const float*)d_in[5];
  float* out = (float*)d_out;

  char* ws = (char*)d_ws;
  __bf16* wqkv_t   = (__bf16*)ws;                  // 50.3MB, dead after gemm1
  __bf16* wo_t     = (__bf16*)(ws + 50331648);     // 33.6MB
  __bf16* hidden_b = (__bf16*)(ws + 83886080);     // 16.8MB, dead after gemm1
  float*  qkv      = (float*)(ws + 100663296);     // 50.3MB
  __bf16* qb  = (__bf16*)ws;                       // q  [T][32][128]
  __bf16* kb  = (__bf16*)(ws + 16777216);          // k  [T][8][128]
  __bf16* vtb = (__bf16*)(ws + 20971520);          // Vt [8][128][T]
  __bf16* attn_o = hidden_b;                       // over dead hidden_b

  k_convert<<<dim3((T_TOK * HID / 4 + 255) / 256), 256, 0, stream>>>(hidden, hidden_b, T_TOK * HID / 4);
  k_transpose<<<dim3(QKV_N / 32, HID / 32), dim3(32, 8), 0, stream>>>(w_qkv, wqkv_t, HID, QKV_N);
  k_transpose<<<dim3(HID / 32, HID / 32), dim3(32, 8), 0, stream>>>(w_o, wo_t, HID, HID);
  k_gemm_bt<<<dim3(QKV_N / 128, T_TOK / 128), 256, 0, stream>>>(hidden_b, wqkv_t, qkv, T_TOK, QKV_N, HID);
  k_norm_rope<<<dim3(48, T_TOK), 64, 0, stream>>>(qkv, positions, q_norm, k_norm, qb, kb, vtb);
  k_attn<<<dim3(512), 256, 0, stream>>>(qb, kb, vtb, attn_o);
  k_gemm_bt<<<dim3(HID / 128, T_TOK / 128), 256, 0, stream>>>(attn_o, wo_t, out, T_TOK, HID, HID);
}

// Round 3
// 361.065 us; speedup vs baseline: 1.9239x; 1.0590x over previous
//
#include <hip/hip_runtime.h>
#include <cstdint>
#include <cstddef>

// ---------------- constants ----------------
#define T_TOK 2048
#define HID   4096
#define NQH   32
#define NKVH  8
#define HD    128
#define QKV_N 6144   // 4096 q + 1024 k + 1024 v

typedef __bf16 bf16x8 __attribute__((ext_vector_type(8)));
typedef __bf16 bf16x4 __attribute__((ext_vector_type(4)));
typedef float  f32x4  __attribute__((ext_vector_type(4)));
typedef float  f32x16 __attribute__((ext_vector_type(16)));

#define AS1 __attribute__((address_space(1)))
#define AS3 __attribute__((address_space(3)))

__device__ __forceinline__ void gll16(const void* g, void* l) {
  __builtin_amdgcn_global_load_lds((const AS1 void*)g, (AS3 void*)l, 16, 0, 0);
}

// ---------------- fp32 -> bf16 convert (vec4) ----------------
__global__ __launch_bounds__(256) void k_convert(const float* __restrict__ in,
                                                 __bf16* __restrict__ out, int n4) {
  int i = blockIdx.x * 256 + threadIdx.x;
  if (i >= n4) return;
  float4 v = ((const float4*)in)[i];
  bf16x4 o;
  o[0] = (__bf16)v.x; o[1] = (__bf16)v.y; o[2] = (__bf16)v.z; o[3] = (__bf16)v.w;
  ((bf16x4*)out)[i] = o;
}

// ---------------- transpose fp32 [R][C] -> bf16 [C][R] ----------------
__global__ __launch_bounds__(256) void k_transpose(const float* __restrict__ in,
                                                   __bf16* __restrict__ out,
                                                   int R, int C) {
  __shared__ float tile[32][33];
  int c0 = blockIdx.x * 32, r0 = blockIdx.y * 32;
  int tx = threadIdx.x, ty = threadIdx.y;  // 32 x 8
#pragma unroll
  for (int k = 0; k < 4; ++k)
    tile[ty + k*8][tx] = in[(size_t)(r0 + ty + k*8) * C + c0 + tx];
  __syncthreads();
#pragma unroll
  for (int k = 0; k < 4; ++k)
    out[(size_t)(c0 + ty + k*8) * R + r0 + tx] = (__bf16)tile[tx][ty + k*8];
}

// ---------------- 8-phase 256x256 bf16 GEMM (T2+T3+T4+T5) -------------------
// C[M][N] = A[M][K] @ Bt[N][K]^T, fp32 out. M=2048 fixed by grid (8 bm rows).
// 512 thr = 8 waves (2M x 4N), per-wave out 128x64. BK=64 as 2 k-chunk regions
// [256 rows][32 cols] per operand, double-buffered (128 KiB LDS).
// Counted vmcnt(6): stage order A0,B0,A1,B1; 1 region staged/phase; waits at
// phases 0/2 only; last K-tile peeled with the single vmcnt(0) drain.
template <int NBNX>
__global__ __launch_bounds__(512, 2) void k_gemm8(const __bf16* __restrict__ A,
                                                  const __bf16* __restrict__ Bt,
                                                  float* __restrict__ C,
                                                  int N, int K) {
  __shared__ alignas(16) char ldsb[131072];
  const int tid = threadIdx.x;
  const int lane = tid & 63, w = tid >> 6;
  const int l16 = lane & 15, lg = lane >> 4;
  const int wm = w >> 2, wn = w & 3;

  // XCD-chunked swizzle: XCD x owns a 4(bm) x NBNX(bn) block patch
  const int x = blockIdx.x & 7, idx = blockIdx.x >> 3;
  const int bm = (x & 1) * 4 + (idx & 3);
  const int bn = (x >> 1) * NBNX + (idx >> 2);

  // staging source pointers: 2 chunks/thread/region; source pre-swizzled with
  // the same involution the reads use (chunk ^ ((row>>1)&3)), LDS stays linear
  const __bf16* asrc[2];
  const __bf16* bsrc[2];
#pragma unroll
  for (int j = 0; j < 2; ++j) {
    int c = (w * 2 + j) * 64 + lane;
    int r = c >> 2;
    int co = ((c & 3) ^ ((r >> 1) & 3)) * 8;
    asrc[j] = A + (size_t)(bm * 256 + r) * K + co;
    bsrc[j] = Bt + (size_t)(bn * 256 + r) * K + co;
  }
  const int dst0 = w * 2048;

#define RA(buf, mk) (ldsb + (buf) * 65536 + (mk) * 16384)
#define RB(buf, mk) (ldsb + (buf) * 65536 + 32768 + (mk) * 16384)
#define STG_A(buf, mk, kk) { gll16(asrc[0] + (kk) + (mk) * 32, RA(buf, mk) + dst0); \
                             gll16(asrc[1] + (kk) + (mk) * 32, RA(buf, mk) + dst0 + 1024); }
#define STG_B(buf, mk, kk) { gll16(bsrc[0] + (kk) + (mk) * 32, RB(buf, mk) + dst0); \
                             gll16(bsrc[1] + (kk) + (mk) * 32, RB(buf, mk) + dst0 + 1024); }
#define FRAG(base, row) (*(const bf16x8*)((base) + (row) * 64 + ((lg ^ (((row) >> 1) & 3)) << 4)))

  f32x4 acc[8][4] = {};
  const int nkt = K >> 6;

  // prologue: stage K-tile 0 into buf 0 (order A0,B0,A1,B1)
  STG_A(0, 0, 0); STG_B(0, 0, 0); STG_A(0, 1, 0); STG_B(0, 1, 0);

  for (int t = 0; t < nkt - 1; ++t) {
    const int cur = t & 1, nxt = cur ^ 1;
    const int kn = (t + 1) * 64;
    bf16x8 a0[4], a1[4], b0[4];

    // ---- phase 0: stage A0(t+1); wait; read mk0 frags; MFMA mi0-3 ----
    STG_A(nxt, 0, kn);
    asm volatile("s_waitcnt vmcnt(6)" ::: "memory");
    __builtin_amdgcn_s_barrier();
    __builtin_amdgcn_sched_barrier(0);
#pragma unroll
    for (int i = 0; i < 4; ++i) a0[i] = FRAG(RA(cur, 0), wm * 128 + i * 16 + l16);
#pragma unroll
    for (int n = 0; n < 4; ++n) b0[n] = FRAG(RB(cur, 0), wn * 64 + n * 16 + l16);
    __builtin_amdgcn_s_setprio(1);
#pragma unroll
    for (int i = 0; i < 4; ++i)
#pragma unroll
      for (int n = 0; n < 4; ++n)
        acc[i][n] = __builtin_amdgcn_mfma_f32_16x16x32_bf16(a0[i], b0[n], acc[i][n], 0, 0, 0);
    __builtin_amdgcn_s_setprio(0);
    __builtin_amdgcn_s_barrier();

    // ---- phase 1: read mi4-7@mk0; stage B0(t+1); MFMA mi4-7 ----
#pragma unroll
    for (int i = 0; i < 4; ++i) a1[i] = FRAG(RA(cur, 0), wm * 128 + 64 + i * 16 + l16);
    STG_B(nxt, 0, kn);
    __builtin_amdgcn_s_barrier();
    __builtin_amdgcn_s_setprio(1);
#pragma unroll
    for (int i = 0; i < 4; ++i)
#pragma unroll
      for (int n = 0; n < 4; ++n)
        acc[4 + i][n] = __builtin_amdgcn_mfma_f32_16x16x32_bf16(a1[i], b0[n], acc[4 + i][n], 0, 0, 0);
    __builtin_amdgcn_s_setprio(0);
    __builtin_amdgcn_s_barrier();

    // ---- phase 2: stage A1(t+1); wait; read mk1 frags; MFMA mi0-3 ----
    STG_A(nxt, 1, kn);
    asm volatile("s_waitcnt vmcnt(6)" ::: "memory");
    __builtin_amdgcn_s_barrier();
    __builtin_amdgcn_sched_barrier(0);
#pragma unroll
    for (int i = 0; i < 4; ++i) a0[i] = FRAG(RA(cur, 1), wm * 128 + i * 16 + l16);
#pragma unroll
    for (int n = 0; n < 4; ++n) b0[n] = FRAG(RB(cur, 1), wn * 64 + n * 16 + l16);
    __builtin_amdgcn_s_setprio(1);
#pragma unroll
    for (int i = 0; i < 4; ++i)
#pragma unroll
      for (int n = 0; n < 4; ++n)
        acc[i][n] = __builtin_amdgcn_mfma_f32_16x16x32_bf16(a0[i], b0[n], acc[i][n], 0, 0, 0);
    __builtin_amdgcn_s_setprio(0);
    __builtin_amdgcn_s_barrier();

    // ---- phase 3: read mi4-7@mk1; stage B1(t+1); MFMA mi4-7 ----
#pragma unroll
    for (int i = 0; i < 4; ++i) a1[i] = FRAG(RA(cur, 1), wm * 128 + 64 + i * 16 + l16);
    STG_B(nxt, 1, kn);
    __builtin_amdgcn_s_barrier();
    __builtin_amdgcn_s_setprio(1);
#pragma unroll
    for (int i = 0; i < 4; ++i)
#pragma unroll
      for (int n = 0; n < 4; ++n)
        acc[4 + i][n] = __builtin_amdgcn_mfma_f32_16x16x32_bf16(a1[i], b0[n], acc[4 + i][n], 0, 0, 0);
    __builtin_amdgcn_s_setprio(0);
    __builtin_amdgcn_s_barrier();
  }

  // ---- peeled last K-tile: single drain, no staging ----
  asm volatile("s_waitcnt vmcnt(0)" ::: "memory");
  __builtin_amdgcn_s_barrier();
  __builtin_amdgcn_sched_barrier(0);
  {
    const int cur = (nkt - 1) & 1;
#pragma unroll
    for (int mk = 0; mk < 2; ++mk) {
      bf16x8 aa[8], bb[4];
#pragma unroll
      for (int i = 0; i < 8; ++i) aa[i] = FRAG(RA(cur, mk), wm * 128 + i * 16 + l16);
#pragma unroll
      for (int n = 0; n < 4; ++n) bb[n] = FRAG(RB(cur, mk), wn * 64 + n * 16 + l16);
#pragma unroll
      for (int i = 0; i < 8; ++i)
#pragma unroll
        for (int n = 0; n < 4; ++n)
          acc[i][n] = __builtin_amdgcn_mfma_f32_16x16x32_bf16(aa[i], bb[n], acc[i][n], 0, 0, 0);
    }
  }
#undef RA
#undef RB
#undef STG_A
#undef STG_B
#undef FRAG

  // ---- epilogue: C/D layout col=lane&15, row=(lane>>4)*4+reg ----
#pragma unroll
  for (int mi = 0; mi < 8; ++mi)
#pragma unroll
    for (int ni = 0; ni < 4; ++ni) {
      int row = bm * 256 + wm * 128 + mi * 16 + lg * 4;
      int col = bn * 256 + wn * 64 + ni * 16 + l16;
#pragma unroll
      for (int r = 0; r < 4; ++r)
        C[(size_t)(row + r) * N + col] = acc[mi][ni][r];
    }
}

// ---------------- per-(token, head-slot) RMSNorm + RoPE -> bf16 ------------
__global__ __launch_bounds__(64) void k_norm_rope(const float* __restrict__ qkv,
                                                  const int* __restrict__ pos,
                                                  const float* __restrict__ qw,
                                                  const float* __restrict__ kw,
                                                  __bf16* __restrict__ qo,
                                                  __bf16* __restrict__ ko,
                                                  __bf16* __restrict__ vto) {
  const int slot = blockIdx.x;   // 0..47
  const int t    = blockIdx.y;   // token
  const int i    = threadIdx.x;  // 0..63
  const int off  = (slot < 32) ? slot * 128
                 : (slot < 40) ? 4096 + (slot - 32) * 128
                                : 5120 + (slot - 40) * 128;
  const float* base = qkv + (size_t)t * QKV_N + off;
  float x1 = base[i], x2 = base[i + 64];
  if (slot >= 40) {
    __bf16* o = vto + ((size_t)(slot - 40) * HD) * T_TOK + t;
    o[(size_t)i * T_TOK] = (__bf16)x1;
    o[(size_t)(i + 64) * T_TOK] = (__bf16)x2;
    return;
  }
  float ss = x1 * x1 + x2 * x2;
#pragma unroll
  for (int m = 32; m >= 1; m >>= 1) ss += __shfl_xor(ss, m);
  float rinv = rsqrtf(ss * (1.0f / 128.0f) + 1e-6f);
  const float* wn = (slot < 32) ? qw : kw;
  float n1 = x1 * rinv * wn[i];
  float n2 = x2 * rinv * wn[i + 64];
  float fr = (float)pos[t] * expf((float)i * -0.21586735246819178f);
  float cs = cosf(fr), sn = sinf(fr);
  float o1 = n1 * cs - n2 * sn;
  float o2 = n2 * cs + n1 * sn;
  if (slot < 32) {
    const float QSC = 0.08838834764831845f * 1.4426950408889634f;
    __bf16* o = qo + ((size_t)t * NQH + slot) * HD;
    o[i] = (__bf16)(o1 * QSC);
    o[i + 64] = (__bf16)(o2 * QSC);
  } else {
    __bf16* o = ko + ((size_t)t * NKVH + (slot - 32)) * HD;
    o[i] = (__bf16)o1;
    o[i + 64] = (__bf16)o2;
  }
}

// ---------------- causal GQA flash attention (32x32 swapped-operand) ---------
__global__ __launch_bounds__(256, 2) void k_attn(const __bf16* __restrict__ Q,
                                                 const __bf16* __restrict__ K,
                                                 const __bf16* __restrict__ Vt,
                                                 __bf16* __restrict__ O) {
  __shared__ alignas(16) __bf16 Ks[64 * 128];    // [kv][d], chunk swz c^(r&15)
  __shared__ alignas(16) __bf16 Vts[128 * 64];   // [d][kv], chunk swz c^(r&7)
  const int bid = blockIdx.x;
  const int kvh = bid & 7;           // kvh == XCD -> K/V L2-local
  const int qc  = bid >> 3;          // 0..63
  const int tid = threadIdx.x, lane = tid & 63, w = tid >> 6;
  const int l31 = lane & 31, hi = lane >> 5;
  const int h  = kvh * 4 + w;        // global q-head
  const int q0 = qc * 32;
  const int qrow = q0 + l31;
  char* Ksb = (char*)Ks;
  char* Vtb = (char*)Vts;

  bf16x8 qf[8];
  {
    const __bf16* qp = Q + ((size_t)qrow * NQH + h) * HD + hi * 8;
#pragma unroll
    for (int dc = 0; dc < 8; ++dc)
      qf[dc] = *(const bf16x8*)(qp + dc * 16);
  }

  size_t ksrc[4], vsrc[4];
#pragma unroll
  for (int j = 0; j < 4; ++j) {
    int kr = w * 16 + j * 4 + (lane >> 4);
    ksrc[j] = ((size_t)kr * NKVH + kvh) * HD + (size_t)(((lane & 15) ^ (kr & 15)) * 8);
    int vr = w * 32 + j * 8 + (lane >> 3);
    vsrc[j] = ((size_t)(kvh * HD + vr)) * T_TOK + (size_t)(((lane & 7) ^ (vr & 7)) * 8);
  }

  float m_run = -3.0e38f, l_run = 0.f;
  f32x16 ot[4] = {};

  const int ntiles = (qc >> 1) + 1;
  for (int tt = 0; tt < ntiles; ++tt) {
    const int s0 = tt * 64;
#pragma unroll
    for (int j = 0; j < 4; ++j) {
      gll16(K + (size_t)s0 * (NKVH * HD) + ksrc[j], Ksb + (w * 4 + j) * 1024);
      gll16(Vt + (size_t)s0 + vsrc[j], Vtb + (w * 4 + j) * 1024);
    }
    __syncthreads();

    f32x16 sac[2] = {};
#pragma unroll
    for (int hf = 0; hf < 2; ++hf) {
      int krow = hf * 32 + l31;
#pragma unroll
      for (int dc = 0; dc < 8; ++dc) {
        bf16x8 kf = *(const bf16x8*)(Ksb + krow * 256 + (((dc * 2 + hi) ^ (krow & 15)) * 16));
        sac[hf] = __builtin_amdgcn_mfma_f32_32x32x16_bf16(kf, qf[dc], sac[hf], 0, 0, 0);
      }
    }

    float pv[32];
    if (s0 + 64 > q0) {
#pragma unroll
      for (int hf = 0; hf < 2; ++hf)
#pragma unroll
        for (int r = 0; r < 16; ++r) {
          int kvg = s0 + hf * 32 + (r & 3) + ((r >> 2) * 8) + hi * 4;
          pv[hf * 16 + r] = (kvg > qrow) ? -3.0e38f : sac[hf][r];
        }
    } else {
#pragma unroll
      for (int hf = 0; hf < 2; ++hf)
#pragma unroll
        for (int r = 0; r < 16; ++r) pv[hf * 16 + r] = sac[hf][r];
    }
    float t16[16];
#pragma unroll
    for (int i = 0; i < 16; ++i) t16[i] = fmaxf(pv[i], pv[i + 16]);
#pragma unroll
    for (int i = 0; i < 8; ++i) t16[i] = fmaxf(t16[i], t16[i + 8]);
#pragma unroll
    for (int i = 0; i < 4; ++i) t16[i] = fmaxf(t16[i], t16[i + 4]);
    float mt = fmaxf(fmaxf(t16[0], t16[1]), fmaxf(t16[2], t16[3]));
    mt = fmaxf(mt, __shfl_xor(mt, 32));
    if (!__all(mt - m_run <= 10.0f)) {
      float m_new = fmaxf(m_run, mt);
      float corr = exp2f(m_run - m_new);
      l_run *= corr;
#pragma unroll
      for (int dt = 0; dt < 4; ++dt)
#pragma unroll
        for (int r = 0; r < 16; ++r) ot[dt][r] *= corr;
      m_run = m_new;
    }
#pragma unroll
    for (int i = 0; i < 32; ++i) pv[i] = exp2f(pv[i] - m_run);
#pragma unroll
    for (int i = 0; i < 16; ++i) t16[i] = pv[i] + pv[i + 16];
#pragma unroll
    for (int i = 0; i < 8; ++i) t16[i] += t16[i + 8];
#pragma unroll
    for (int i = 0; i < 4; ++i) t16[i] += t16[i + 4];
    float rs = (t16[0] + t16[1]) + (t16[2] + t16[3]);
    rs += __shfl_xor(rs, 32);
    l_run += rs;

    uint32_t wds[16];
#pragma unroll
    for (int i = 0; i < 16; ++i) {
      uint32_t r;
      asm("v_cvt_pk_bf16_f32 %0, %1, %2" : "=v"(r) : "v"(pv[2 * i]), "v"(pv[2 * i + 1]));
      wds[i] = r;
    }
#pragma unroll
    for (int c = 0; c < 4; ++c) {
      const int base = (c >> 1) * 8 + (c & 1) * 4;
      uint32_t sa = hi ? wds[base + 0] : wds[base + 2];
      uint32_t sb = hi ? wds[base + 1] : wds[base + 3];
      uint32_t ra = __shfl_xor(sa, 32);
      uint32_t rb = __shfl_xor(sb, 32);
      union { uint32_t u[4]; bf16x8 v; } pf;
      pf.u[0] = hi ? ra : wds[base + 0];
      pf.u[1] = hi ? rb : wds[base + 1];
      pf.u[2] = hi ? wds[base + 2] : ra;
      pf.u[3] = hi ? wds[base + 3] : rb;
#pragma unroll
      for (int dt = 0; dt < 4; ++dt) {
        int vrow = dt * 32 + l31;
        bf16x8 vf = *(const bf16x8*)(Vtb + vrow * 128 + (((c * 2 + hi) ^ (vrow & 7)) * 16));
        ot[dt] = __builtin_amdgcn_mfma_f32_32x32x16_bf16(vf, pf.v, ot[dt], 0, 0, 0);
      }
    }
    __syncthreads();
  }

  float inv = 1.0f / l_run;
  char* Ob = Ksb + w * 8192;
#pragma unroll
  for (int dt = 0; dt < 4; ++dt)
#pragma unroll
    for (int r = 0; r < 16; ++r) {
      int d = dt * 32 + (r & 3) + ((r >> 2) * 8) + hi * 4;
      *(__bf16*)(Ob + l31 * 256 + ((d * 2) ^ ((l31 & 7) << 4))) = (__bf16)(ot[dt][r] * inv);
    }
#pragma unroll
  for (int pass = 0; pass < 8; ++pass) {
    int q = pass * 4 + (lane >> 4);
    int ch = lane & 15;
    bf16x8 vvv = *(const bf16x8*)(Ob + q * 256 + ((ch ^ (q & 7)) * 16));
    *(bf16x8*)(O + ((size_t)(q0 + q) * NQH + h) * HD + ch * 8) = vvv;
  }
}

// ---------------- launch ----------------------------------------------------
extern "C" void kernel_launch(void* const* d_in, const int* in_sizes, int n_in,
                              void* d_out, int out_size, void* d_ws, size_t ws_size,
                              hipStream_t stream) {
  const int*   positions = (const int*)d_in[0];
  const float* hidden    = (const float*)d_in[1];
  const float* w_qkv     = (const float*)d_in[2];
  const float* w_o       = (const float*)d_in[3];
  const float* q_norm    = (const float*)d_in[4];
  const float* k_norm    = (const float*)d_in[5];
  float* out = (float*)d_out;

  char* ws = (char*)d_ws;
  __bf16* wqkv_t   = (__bf16*)ws;                  // 50.3MB, dead after gemm1
  __bf16* wo_t     = (__bf16*)(ws + 50331648);     // 33.6MB
  __bf16* hidden_b = (__bf16*)(ws + 83886080);     // 16.8MB, dead after gemm1
  float*  qkv      = (float*)(ws + 100663296);     // 50.3MB
  __bf16* qb  = (__bf16*)ws;                       // q  [T][32][128]
  __bf16* kb  = (__bf16*)(ws + 16777216);          // k  [T][8][128]
  __bf16* vtb = (__bf16*)(ws + 20971520);          // Vt [8][128][T]
  __bf16* attn_o = hidden_b;                       // over dead hidden_b

  k_convert<<<dim3((T_TOK * HID / 4 + 255) / 256), 256, 0, stream>>>(hidden, hidden_b, T_TOK * HID / 4);
  k_transpose<<<dim3(QKV_N / 32, HID / 32), dim3(32, 8), 0, stream>>>(w_qkv, wqkv_t, HID, QKV_N);
  k_transpose<<<dim3(HID / 32, HID / 32), dim3(32, 8), 0, stream>>>(w_o, wo_t, HID, HID);
  k_gemm8<6><<<dim3(192), 512, 0, stream>>>(hidden_b, wqkv_t, qkv, QKV_N, HID);
  k_norm_rope<<<dim3(48, T_TOK), 64, 0, stream>>>(qkv, positions, q_norm, k_norm, qb, kb, vtb);
  k_attn<<<dim3(512), 256, 0, stream>>>(qb, kb, vtb, attn_o);
  k_gemm8<4><<<dim3(128), 512, 0, stream>>>(attn_o, wo_t, out, HID, HID);
}

// Round 4
// 327.900 us; speedup vs baseline: 2.1185x; 1.1011x over previous
//
#include <hip/hip_runtime.h>
#include <cstdint>
#include <cstddef>

// ---------------- constants ----------------
#define T_TOK 2048
#define HID   4096
#define NQH   32
#define NKVH  8
#define HD    128
#define QKV_N 6144   // 4096 q + 1024 k + 1024 v

typedef __bf16 bf16x8 __attribute__((ext_vector_type(8)));
typedef __bf16 bf16x4 __attribute__((ext_vector_type(4)));
typedef float  f32x4  __attribute__((ext_vector_type(4)));
typedef float  f32x16 __attribute__((ext_vector_type(16)));

#define AS1 __attribute__((address_space(1)))
#define AS3 __attribute__((address_space(3)))

__device__ __forceinline__ void gll16(const void* g, void* l) {
  __builtin_amdgcn_global_load_lds((const AS1 void*)g, (AS3 void*)l, 16, 0, 0);
}

// ---------------- fp32 -> bf16 convert (vec4) ----------------
__global__ __launch_bounds__(256) void k_convert(const float* __restrict__ in,
                                                 __bf16* __restrict__ out, int n4) {
  int i = blockIdx.x * 256 + threadIdx.x;
  if (i >= n4) return;
  float4 v = ((const float4*)in)[i];
  bf16x4 o;
  o[0] = (__bf16)v.x; o[1] = (__bf16)v.y; o[2] = (__bf16)v.z; o[3] = (__bf16)v.w;
  ((bf16x4*)out)[i] = o;
}

// ---------------- transpose fp32 [R][C] -> bf16 [C][R] ----------------
__global__ __launch_bounds__(256) void k_transpose(const float* __restrict__ in,
                                                   __bf16* __restrict__ out,
                                                   int R, int C) {
  __shared__ float tile[32][33];
  int c0 = blockIdx.x * 32, r0 = blockIdx.y * 32;
  int tx = threadIdx.x, ty = threadIdx.y;  // 32 x 8
#pragma unroll
  for (int k = 0; k < 4; ++k)
    tile[ty + k*8][tx] = in[(size_t)(r0 + ty + k*8) * C + c0 + tx];
  __syncthreads();
#pragma unroll
  for (int k = 0; k < 4; ++k)
    out[(size_t)(c0 + ty + k*8) * R + r0 + tx] = (__bf16)tile[tx][ty + k*8];
}

// ---------------- 8-phase bf16 GEMM, BM=128 x BN=64*NFR (T2+T3+T4+T5) -------
// C[M][N] = A[M][K] @ Bt[N][K]^T, fp32 out. Grid = 16(bm) x 16(bn) = 256 blocks
// exactly (one per CU, single round). 512 thr = 8 waves (2M x 4N), per-wave
// out 64 x 16*NFR. BK=64 as 2 k-chunk regions [rows][32 cols] per operand,
// double-buffered. Counted vmcnt(NB+1): stage order A0,B0,A1,B1, one region
// per phase; waits at phases 0/2 only; last K-tile peeled with vmcnt(0).
// NFR=6 -> BN=384 (gemm1, N=6144); NFR=4 -> BN=256 (gemm2, N=4096).
template <int NFR>
__global__ __launch_bounds__(512, 2) void k_gemm8(const __bf16* __restrict__ A,
                                                  const __bf16* __restrict__ Bt,
                                                  float* __restrict__ C,
                                                  int N, int K) {
  constexpr int BN   = 64 * NFR;      // block N
  constexpr int WN   = 16 * NFR;      // wave N
  constexpr int NB   = NFR / 2;       // B-region gll chunks per thread
  constexpr int NH   = NFR / 2;       // n-frags per phase
  constexpr int BREG = BN * 64;       // B k-chunk region bytes ([BN][32]x2B)
  constexpr int BUFSZ = 16384 + 2 * BREG;
  __shared__ alignas(16) char ldsb[2 * BUFSZ];
  const int tid = threadIdx.x;
  const int lane = tid & 63, w = tid >> 6;
  const int l16 = lane & 15, lg = lane >> 4;
  const int wm = w >> 2, wn = w & 3;

  // XCD-chunked swizzle over the 16x16 grid: XCD x owns 8(bm) x 4(bn)
  const int x = blockIdx.x & 7, idx = blockIdx.x >> 3;
  const int bm = (x & 1) * 8 + (idx & 7);
  const int bn = (x >> 1) * 4 + (idx >> 3);

  // staging sources, pre-swizzled with the read involution (chunk ^ ((row>>1)&3))
  const int rA = tid >> 2, pA = tid & 3;
  const __bf16* asrc = A + (size_t)(bm * 128 + rA) * K + ((pA ^ ((rA >> 1) & 3)) * 8);
  const __bf16* bsrc = Bt + (size_t)(bn * BN + rA) * K + ((pA ^ ((rA >> 1) & 3)) * 8);

#define RA_(buf, mk) (ldsb + (buf) * BUFSZ + (mk) * 8192)
#define RB_(buf, mk) (ldsb + (buf) * BUFSZ + 16384 + (mk) * BREG)
#define STG_A(buf, mk, kk) { gll16(asrc + (kk) + (mk) * 32, RA_(buf, mk) + w * 1024); }
#define STG_B(buf, mk, kk) { _Pragma("unroll") \
    for (int j = 0; j < NB; ++j) \
      gll16(bsrc + (size_t)j * 128 * K + (kk) + (mk) * 32, RB_(buf, mk) + j * 8192 + w * 1024); }
#define FRAG(base, row) (*(const bf16x8*)((base) + (row) * 64 + ((lg ^ (((row) >> 1) & 3)) << 4)))
#define WAITN() { if constexpr (NFR == 6) asm volatile("s_waitcnt vmcnt(4)" ::: "memory"); \
                  else                    asm volatile("s_waitcnt vmcnt(3)" ::: "memory"); }

  f32x4 acc[4][NFR] = {};
  const int nkt = K >> 6;

  // prologue: stage K-tile 0 into buf 0 (order A0,B0,A1,B1)
  STG_A(0, 0, 0); STG_B(0, 0, 0); STG_A(0, 1, 0); STG_B(0, 1, 0);

  for (int t = 0; t < nkt - 1; ++t) {
    const int cur = t & 1, nxt = cur ^ 1;
    const int kn = (t + 1) * 64;
    bf16x8 af[4], bf_[NH];

    // ---- phase 0: stage A0(t+1); wait; read mk0 A + B lo; MFMA ni[0,NH) ----
    STG_A(nxt, 0, kn);
    WAITN();
    __builtin_amdgcn_s_barrier();
    __builtin_amdgcn_sched_barrier(0);
#pragma unroll
    for (int i = 0; i < 4; ++i) af[i] = FRAG(RA_(cur, 0), wm * 64 + i * 16 + l16);
#pragma unroll
    for (int n = 0; n < NH; ++n) bf_[n] = FRAG(RB_(cur, 0), wn * WN + n * 16 + l16);
    __builtin_amdgcn_s_setprio(1);
#pragma unroll
    for (int i = 0; i < 4; ++i)
#pragma unroll
      for (int n = 0; n < NH; ++n)
        acc[i][n] = __builtin_amdgcn_mfma_f32_16x16x32_bf16(af[i], bf_[n], acc[i][n], 0, 0, 0);
    __builtin_amdgcn_s_setprio(0);
    __builtin_amdgcn_s_barrier();

    // ---- phase 1: read B hi @mk0; stage B0(t+1); MFMA ni[NH,NFR) ----
#pragma unroll
    for (int n = 0; n < NH; ++n) bf_[n] = FRAG(RB_(cur, 0), wn * WN + (NH + n) * 16 + l16);
    STG_B(nxt, 0, kn);
    __builtin_amdgcn_s_barrier();
    __builtin_amdgcn_s_setprio(1);
#pragma unroll
    for (int i = 0; i < 4; ++i)
#pragma unroll
      for (int n = 0; n < NH; ++n)
        acc[i][NH + n] = __builtin_amdgcn_mfma_f32_16x16x32_bf16(af[i], bf_[n], acc[i][NH + n], 0, 0, 0);
    __builtin_amdgcn_s_setprio(0);
    __builtin_amdgcn_s_barrier();

    // ---- phase 2: stage A1(t+1); wait; read mk1 A + B lo; MFMA ni[0,NH) ----
    STG_A(nxt, 1, kn);
    WAITN();
    __builtin_amdgcn_s_barrier();
    __builtin_amdgcn_sched_barrier(0);
#pragma unroll
    for (int i = 0; i < 4; ++i) af[i] = FRAG(RA_(cur, 1), wm * 64 + i * 16 + l16);
#pragma unroll
    for (int n = 0; n < NH; ++n) bf_[n] = FRAG(RB_(cur, 1), wn * WN + n * 16 + l16);
    __builtin_amdgcn_s_setprio(1);
#pragma unroll
    for (int i = 0; i < 4; ++i)
#pragma unroll
      for (int n = 0; n < NH; ++n)
        acc[i][n] = __builtin_amdgcn_mfma_f32_16x16x32_bf16(af[i], bf_[n], acc[i][n], 0, 0, 0);
    __builtin_amdgcn_s_setprio(0);
    __builtin_amdgcn_s_barrier();

    // ---- phase 3: read B hi @mk1; stage B1(t+1); MFMA ni[NH,NFR) ----
#pragma unroll
    for (int n = 0; n < NH; ++n) bf_[n] = FRAG(RB_(cur, 1), wn * WN + (NH + n) * 16 + l16);
    STG_B(nxt, 1, kn);
    __builtin_amdgcn_s_barrier();
    __builtin_amdgcn_s_setprio(1);
#pragma unroll
    for (int i = 0; i < 4; ++i)
#pragma unroll
      for (int n = 0; n < NH; ++n)
        acc[i][NH + n] = __builtin_amdgcn_mfma_f32_16x16x32_bf16(af[i], bf_[n], acc[i][NH + n], 0, 0, 0);
    __builtin_amdgcn_s_setprio(0);
    __builtin_amdgcn_s_barrier();
  }

  // ---- peeled last K-tile: single drain, no staging ----
  asm volatile("s_waitcnt vmcnt(0)" ::: "memory");
  __builtin_amdgcn_s_barrier();
  __builtin_amdgcn_sched_barrier(0);
  {
    const int cur = (nkt - 1) & 1;
#pragma unroll
    for (int mk = 0; mk < 2; ++mk) {
      bf16x8 aa[4], bb[NFR];
#pragma unroll
      for (int i = 0; i < 4; ++i) aa[i] = FRAG(RA_(cur, mk), wm * 64 + i * 16 + l16);
#pragma unroll
      for (int n = 0; n < NFR; ++n) bb[n] = FRAG(RB_(cur, mk), wn * WN + n * 16 + l16);
#pragma unroll
      for (int i = 0; i < 4; ++i)
#pragma unroll
        for (int n = 0; n < NFR; ++n)
          acc[i][n] = __builtin_amdgcn_mfma_f32_16x16x32_bf16(aa[i], bb[n], acc[i][n], 0, 0, 0);
    }
  }
#undef RA_
#undef RB_
#undef STG_A
#undef STG_B
#undef FRAG
#undef WAITN

  // ---- epilogue: C/D layout col=lane&15, row=(lane>>4)*4+reg ----
#pragma unroll
  for (int mi = 0; mi < 4; ++mi)
#pragma unroll
    for (int ni = 0; ni < NFR; ++ni) {
      int row = bm * 128 + wm * 64 + mi * 16 + lg * 4;
      int col = bn * BN + wn * WN + ni * 16 + l16;
#pragma unroll
      for (int r = 0; r < 4; ++r)
        C[(size_t)(row + r) * N + col] = acc[mi][ni][r];
    }
}

// ---------------- per-(token, head-slot) RMSNorm + RoPE -> bf16 ------------
__global__ __launch_bounds__(64) void k_norm_rope(const float* __restrict__ qkv,
                                                  const int* __restrict__ pos,
                                                  const float* __restrict__ qw,
                                                  const float* __restrict__ kw,
                                                  __bf16* __restrict__ qo,
                                                  __bf16* __restrict__ ko,
                                                  __bf16* __restrict__ vto) {
  const int slot = blockIdx.x;   // 0..47
  const int t    = blockIdx.y;   // token
  const int i    = threadIdx.x;  // 0..63
  const int off  = (slot < 32) ? slot * 128
                 : (slot < 40) ? 4096 + (slot - 32) * 128
                                : 5120 + (slot - 40) * 128;
  const float* base = qkv + (size_t)t * QKV_N + off;
  float x1 = base[i], x2 = base[i + 64];
  if (slot >= 40) {
    __bf16* o = vto + ((size_t)(slot - 40) * HD) * T_TOK + t;
    o[(size_t)i * T_TOK] = (__bf16)x1;
    o[(size_t)(i + 64) * T_TOK] = (__bf16)x2;
    return;
  }
  float ss = x1 * x1 + x2 * x2;
#pragma unroll
  for (int m = 32; m >= 1; m >>= 1) ss += __shfl_xor(ss, m);
  float rinv = rsqrtf(ss * (1.0f / 128.0f) + 1e-6f);
  const float* wn = (slot < 32) ? qw : kw;
  float n1 = x1 * rinv * wn[i];
  float n2 = x2 * rinv * wn[i + 64];
  float fr = (float)pos[t] * expf((float)i * -0.21586735246819178f);
  float cs = cosf(fr), sn = sinf(fr);
  float o1 = n1 * cs - n2 * sn;
  float o2 = n2 * cs + n1 * sn;
  if (slot < 32) {
    const float QSC = 0.08838834764831845f * 1.4426950408889634f;
    __bf16* o = qo + ((size_t)t * NQH + slot) * HD;
    o[i] = (__bf16)(o1 * QSC);
    o[i + 64] = (__bf16)(o2 * QSC);
  } else {
    __bf16* o = ko + ((size_t)t * NKVH + (slot - 32)) * HD;
    o[i] = (__bf16)o1;
    o[i + 64] = (__bf16)o2;
  }
}

// ---------------- causal GQA flash attention (32x32 swapped-operand) ---------
__global__ __launch_bounds__(256, 2) void k_attn(const __bf16* __restrict__ Q,
                                                 const __bf16* __restrict__ K,
                                                 const __bf16* __restrict__ Vt,
                                                 __bf16* __restrict__ O) {
  __shared__ alignas(16) __bf16 Ks[64 * 128];    // [kv][d], chunk swz c^(r&15)
  __shared__ alignas(16) __bf16 Vts[128 * 64];   // [d][kv], chunk swz c^(r&7)
  const int bid = blockIdx.x;
  const int kvh = bid & 7;           // kvh == XCD -> K/V L2-local
  const int qc  = bid >> 3;          // 0..63
  const int tid = threadIdx.x, lane = tid & 63, w = tid >> 6;
  const int l31 = lane & 31, hi = lane >> 5;
  const int h  = kvh * 4 + w;        // global q-head
  const int q0 = qc * 32;
  const int qrow = q0 + l31;
  char* Ksb = (char*)Ks;
  char* Vtb = (char*)Vts;

  bf16x8 qf[8];
  {
    const __bf16* qp = Q + ((size_t)qrow * NQH + h) * HD + hi * 8;
#pragma unroll
    for (int dc = 0; dc < 8; ++dc)
      qf[dc] = *(const bf16x8*)(qp + dc * 16);
  }

  size_t ksrc[4], vsrc[4];
#pragma unroll
  for (int j = 0; j < 4; ++j) {
    int kr = w * 16 + j * 4 + (lane >> 4);
    ksrc[j] = ((size_t)kr * NKVH + kvh) * HD + (size_t)(((lane & 15) ^ (kr & 15)) * 8);
    int vr = w * 32 + j * 8 + (lane >> 3);
    vsrc[j] = ((size_t)(kvh * HD + vr)) * T_TOK + (size_t)(((lane & 7) ^ (vr & 7)) * 8);
  }

  float m_run = -3.0e38f, l_run = 0.f;
  f32x16 ot[4] = {};

  const int ntiles = (qc >> 1) + 1;
  for (int tt = 0; tt < ntiles; ++tt) {
    const int s0 = tt * 64;
#pragma unroll
    for (int j = 0; j < 4; ++j) {
      gll16(K + (size_t)s0 * (NKVH * HD) + ksrc[j], Ksb + (w * 4 + j) * 1024);
      gll16(Vt + (size_t)s0 + vsrc[j], Vtb + (w * 4 + j) * 1024);
    }
    __syncthreads();

    f32x16 sac[2] = {};
#pragma unroll
    for (int hf = 0; hf < 2; ++hf) {
      int krow = hf * 32 + l31;
#pragma unroll
      for (int dc = 0; dc < 8; ++dc) {
        bf16x8 kf = *(const bf16x8*)(Ksb + krow * 256 + (((dc * 2 + hi) ^ (krow & 15)) * 16));
        sac[hf] = __builtin_amdgcn_mfma_f32_32x32x16_bf16(kf, qf[dc], sac[hf], 0, 0, 0);
      }
    }

    float pv[32];
    if (s0 + 64 > q0) {
#pragma unroll
      for (int hf = 0; hf < 2; ++hf)
#pragma unroll
        for (int r = 0; r < 16; ++r) {
          int kvg = s0 + hf * 32 + (r & 3) + ((r >> 2) * 8) + hi * 4;
          pv[hf * 16 + r] = (kvg > qrow) ? -3.0e38f : sac[hf][r];
        }
    } else {
#pragma unroll
      for (int hf = 0; hf < 2; ++hf)
#pragma unroll
        for (int r = 0; r < 16; ++r) pv[hf * 16 + r] = sac[hf][r];
    }
    float t16[16];
#pragma unroll
    for (int i = 0; i < 16; ++i) t16[i] = fmaxf(pv[i], pv[i + 16]);
#pragma unroll
    for (int i = 0; i < 8; ++i) t16[i] = fmaxf(t16[i], t16[i + 8]);
#pragma unroll
    for (int i = 0; i < 4; ++i) t16[i] = fmaxf(t16[i], t16[i + 4]);
    float mt = fmaxf(fmaxf(t16[0], t16[1]), fmaxf(t16[2], t16[3]));
    mt = fmaxf(mt, __shfl_xor(mt, 32));
    if (!__all(mt - m_run <= 10.0f)) {
      float m_new = fmaxf(m_run, mt);
      float corr = exp2f(m_run - m_new);
      l_run *= corr;
#pragma unroll
      for (int dt = 0; dt < 4; ++dt)
#pragma unroll
        for (int r = 0; r < 16; ++r) ot[dt][r] *= corr;
      m_run = m_new;
    }
#pragma unroll
    for (int i = 0; i < 32; ++i) pv[i] = exp2f(pv[i] - m_run);
#pragma unroll
    for (int i = 0; i < 16; ++i) t16[i] = pv[i] + pv[i + 16];
#pragma unroll
    for (int i = 0; i < 8; ++i) t16[i] += t16[i + 8];
#pragma unroll
    for (int i = 0; i < 4; ++i) t16[i] += t16[i + 4];
    float rs = (t16[0] + t16[1]) + (t16[2] + t16[3]);
    rs += __shfl_xor(rs, 32);
    l_run += rs;

    uint32_t wds[16];
#pragma unroll
    for (int i = 0; i < 16; ++i) {
      uint32_t r;
      asm("v_cvt_pk_bf16_f32 %0, %1, %2" : "=v"(r) : "v"(pv[2 * i]), "v"(pv[2 * i + 1]));
      wds[i] = r;
    }
#pragma unroll
    for (int c = 0; c < 4; ++c) {
      const int base = (c >> 1) * 8 + (c & 1) * 4;
      uint32_t sa = hi ? wds[base + 0] : wds[base + 2];
      uint32_t sb = hi ? wds[base + 1] : wds[base + 3];
      uint32_t ra = __shfl_xor(sa, 32);
      uint32_t rb = __shfl_xor(sb, 32);
      union { uint32_t u[4]; bf16x8 v; } pf;
      pf.u[0] = hi ? ra : wds[base + 0];
      pf.u[1] = hi ? rb : wds[base + 1];
      pf.u[2] = hi ? wds[base + 2] : ra;
      pf.u[3] = hi ? wds[base + 3] : rb;
#pragma unroll
      for (int dt = 0; dt < 4; ++dt) {
        int vrow = dt * 32 + l31;
        bf16x8 vf = *(const bf16x8*)(Vtb + vrow * 128 + (((c * 2 + hi) ^ (vrow & 7)) * 16));
        ot[dt] = __builtin_amdgcn_mfma_f32_32x32x16_bf16(vf, pf.v, ot[dt], 0, 0, 0);
      }
    }
    __syncthreads();
  }

  float inv = 1.0f / l_run;
  char* Ob = Ksb + w * 8192;
#pragma unroll
  for (int dt = 0; dt < 4; ++dt)
#pragma unroll
    for (int r = 0; r < 16; ++r) {
      int d = dt * 32 + (r & 3) + ((r >> 2) * 8) + hi * 4;
      *(__bf16*)(Ob + l31 * 256 + ((d * 2) ^ ((l31 & 7) << 4))) = (__bf16)(ot[dt][r] * inv);
    }
#pragma unroll
  for (int pass = 0; pass < 8; ++pass) {
    int q = pass * 4 + (lane >> 4);
    int ch = lane & 15;
    bf16x8 vvv = *(const bf16x8*)(Ob + q * 256 + ((ch ^ (q & 7)) * 16));
    *(bf16x8*)(O + ((size_t)(q0 + q) * NQH + h) * HD + ch * 8) = vvv;
  }
}

// ---------------- launch ----------------------------------------------------
extern "C" void kernel_launch(void* const* d_in, const int* in_sizes, int n_in,
                              void* d_out, int out_size, void* d_ws, size_t ws_size,
                              hipStream_t stream) {
  const int*   positions = (const int*)d_in[0];
  const float* hidden    = (const float*)d_in[1];
  const float* w_qkv     = (const float*)d_in[2];
  const float* w_o       = (const float*)d_in[3];
  const float* q_norm    = (const float*)d_in[4];
  const float* k_norm    = (const float*)d_in[5];
  float* out = (float*)d_out;

  char* ws = (char*)d_ws;
  __bf16* wqkv_t   = (__bf16*)ws;                  // 50.3MB, dead after gemm1
  __bf16* wo_t     = (__bf16*)(ws + 50331648);     // 33.6MB
  __bf16* hidden_b = (__bf16*)(ws + 83886080);     // 16.8MB, dead after gemm1
  float*  qkv      = (float*)(ws + 100663296);     // 50.3MB
  __bf16* qb  = (__bf16*)ws;                       // q  [T][32][128]
  __bf16* kb  = (__bf16*)(ws + 16777216);          // k  [T][8][128]
  __bf16* vtb = (__bf16*)(ws + 20971520);          // Vt [8][128][T]
  __bf16* attn_o = hidden_b;                       // over dead hidden_b

  k_convert<<<dim3((T_TOK * HID / 4 + 255) / 256), 256, 0, stream>>>(hidden, hidden_b, T_TOK * HID / 4);
  k_transpose<<<dim3(QKV_N / 32, HID / 32), dim3(32, 8), 0, stream>>>(w_qkv, wqkv_t, HID, QKV_N);
  k_transpose<<<dim3(HID / 32, HID / 32), dim3(32, 8), 0, stream>>>(w_o, wo_t, HID, HID);
  k_gemm8<6><<<dim3(256), 512, 0, stream>>>(hidden_b, wqkv_t, qkv, QKV_N, HID);
  k_norm_rope<<<dim3(48, T_TOK), 64, 0, stream>>>(qkv, positions, q_norm, k_norm, qb, kb, vtb);
  k_attn<<<dim3(512), 256, 0, stream>>>(qb, kb, vtb, attn_o);
  k_gemm8<4><<<dim3(256), 512, 0, stream>>>(attn_o, wo_t, out, HID, HID);
}